// Round 2
// baseline (239.597 us; speedup 1.0000x reference)
//
#include <hip/hip_runtime.h>
#include <hip/hip_bf16.h>
#include <math.h>

#define NB   16      // batch
#define NTOK 4096    // N = 64*64
#define DIM  128
#define NE   8
#define HID  512
#define NOUT 128

static __device__ __forceinline__ float bf2f(unsigned int u16) {
    union { unsigned int i; float f; } v;
    v.i = (u16 & 0xffffu) << 16;
    return v.f;
}

static __device__ __forceinline__ unsigned short f2bf(float f) {
    union { float f; unsigned int i; } v;
    v.f = f;
    unsigned int i = v.i;
    unsigned int lsb = (i >> 16) & 1u;
    i += 0x7fffu + lsb;   // round-to-nearest-even
    return (unsigned short)(i >> 16);
}

template<bool F32>
static __device__ __forceinline__ float ld(const void* p, size_t i) {
    if (F32) return ((const float*)p)[i];
    return bf2f(((const unsigned short*)p)[i]);
}

template<bool F32>
static __device__ __forceinline__ void st(void* p, size_t i, float v) {
    if (F32) ((float*)p)[i] = v;
    else ((unsigned short*)p)[i] = f2bf(v);
}

// ws layout: s0[16*8] floats (512 B) | hit[16] u32 (64 B) | flag u32
// Detect dtype: if x is fp32, even-index 16-bit halves are mantissa garbage
// (random exponents -> huge/NaN). If bf16, all samples are |v| <~ 6.
__global__ __launch_bounds__(64) void detect_kernel(
    const unsigned short* __restrict__ x,
    float* __restrict__ s0, unsigned int* __restrict__ hit,
    unsigned int* __restrict__ flag)
{
    int tid = threadIdx.x;
    s0[tid] = 0.f; s0[tid + 64] = 0.f;
    if (tid < NB) hit[tid] = 0u;
    float v = bf2f(x[(size_t)tid * 131072ull]);   // even ushort index
    int bad = !(fabsf(v) <= 1e4f);                // catches NaN and huge
    unsigned long long bal = __ballot(bad);
    if (tid == 0) *flag = bal ? 1u : 0u;          // 1 => fp32 data
}

// One thread per token: gate logits -> argmax (hit bitmask via wave ballot),
// softmax score for expert 0 at n<8, and zero-fill this token's output row.
template<bool F32>
__global__ __launch_bounds__(256) void gate_kernel(
    const void* __restrict__ x,    // (16,4096,128)
    const void* __restrict__ wg,   // (128,8)
    const void* __restrict__ bg,   // (8)
    float* __restrict__ s0,        // ws (16,8)
    unsigned int* __restrict__ hit,// ws (16)
    const unsigned int* __restrict__ flag,
    void* __restrict__ out)        // (16,4096,128)
{
    if ((*flag != 0) != F32) return;

    __shared__ float lwg[DIM][NE];   // 4 KB
    __shared__ float lbg[NE];
    int tid = threadIdx.x;
    for (int i = tid; i < DIM * NE; i += 256) lwg[i / NE][i % NE] = ld<F32>(wg, i);
    if (tid < NE) lbg[tid] = ld<F32>(bg, tid);
    __syncthreads();

    int t = blockIdx.x * 256 + tid;   // token id 0..65535 (exact grid)
    int b = t >> 12;                  // wave-uniform (4096 % 256 == 0)
    int n = t & 4095;

    float z[NE];
    #pragma unroll
    for (int e = 0; e < NE; e++) z[e] = lbg[e];

    const char* xrow = (const char*)x + (size_t)t * DIM * (F32 ? 4 : 2);
    if (F32) {
        const float4* xr = (const float4*)xrow;
        #pragma unroll
        for (int i = 0; i < DIM / 4; i++) {
            float4 p = xr[i];
            float xf[4] = {p.x, p.y, p.z, p.w};
            #pragma unroll
            for (int j = 0; j < 4; j++) {
                int d = i * 4 + j;
                #pragma unroll
                for (int e = 0; e < NE; e++) z[e] += xf[j] * lwg[d][e];
            }
        }
    } else {
        const uint4* xr = (const uint4*)xrow;
        #pragma unroll
        for (int i = 0; i < DIM / 8; i++) {
            uint4 p = xr[i];
            float xf[8];
            xf[0] = bf2f(p.x); xf[1] = bf2f(p.x >> 16);
            xf[2] = bf2f(p.y); xf[3] = bf2f(p.y >> 16);
            xf[4] = bf2f(p.z); xf[5] = bf2f(p.z >> 16);
            xf[6] = bf2f(p.w); xf[7] = bf2f(p.w >> 16);
            #pragma unroll
            for (int j = 0; j < 8; j++) {
                int d = i * 8 + j;
                #pragma unroll
                for (int e = 0; e < NE; e++) z[e] += xf[j] * lwg[d][e];
            }
        }
    }

    // argmax (first occurrence of max, matching jnp.argmax)
    int am = 0;
    float mz = z[0];
    #pragma unroll
    for (int e = 1; e < NE; e++) {
        if (z[e] > mz) { mz = z[e]; am = e; }
    }

    // hit bitmask: at most one atomic per (wave, expert)
    #pragma unroll
    for (int e = 0; e < NE; e++) {
        unsigned long long bal = __ballot(am == e);
        if ((tid & 63) == 0 && bal) atomicOr(&hit[b], 1u << e);
    }

    // softmax score for expert 0 at token positions n<8
    if (n < 8) {
        float mx = z[0];
        #pragma unroll
        for (int e = 1; e < NE; e++) mx = fmaxf(mx, z[e]);
        float s = 0.f;
        #pragma unroll
        for (int e = 0; e < NE; e++) s += expf(z[e] - mx);
        s0[b * NE + n] = expf(z[0] - mx) / s;
    }

    // zero-fill this token's output row (expert kernel overwrites n<8 later)
    uint4 zz = make_uint4(0, 0, 0, 0);
    uint4* orow = (uint4*)((char*)out + (size_t)t * NOUT * (F32 ? 4 : 2));
    const int nq = F32 ? (NOUT * 4 / 16) : (NOUT * 2 / 16);
    #pragma unroll
    for (int i = 0; i < nq; i++) orow[i] = zz;
}

// One block per batch image. Expert-0 MixFFN for the 8 nonzero tokens:
// fc1 at 18 positions (rows 0-1, cols 0-8) -> dwconv(h=0,w=0..7) -> gelu ->
// fc2, scaled by the (buggy-scatter) gate.
template<bool F32>
__global__ __launch_bounds__(512) void expert_kernel(
    const void* __restrict__ x,
    const void* __restrict__ W1,   // (8,128,512) -> expert 0 slice
    const void* __restrict__ B1,   // (8,512)
    const void* __restrict__ Wd,   // (8,3,3,1,512)
    const void* __restrict__ Bd,   // (8,512)
    const void* __restrict__ W2,   // (8,512,128)
    const void* __restrict__ B2,   // (8,128)
    const float* __restrict__ s0,
    const unsigned int* __restrict__ hit,
    const unsigned int* __restrict__ flag,
    void* __restrict__ out)
{
    if ((*flag != 0) != F32) return;

    __shared__ float xs[18][DIM];     //  9216 B
    __shared__ float h1[2][9][HID];   // 36864 B
    __shared__ float gl[8][HID];      // 16384 B
    __shared__ float gate[8];         // total ~62.5 KB

    int b = blockIdx.x;
    int tid = threadIdx.x;

    // stage x at (row 0..1, col 0..8)
    for (int i = tid; i < 18 * DIM; i += 512) {
        int p = i / DIM, d = i % DIM;
        int row = p / 9, col = p % 9;
        int n = row * 64 + col;
        xs[p][d] = ld<F32>(x, ((size_t)b * NTOK + n) * DIM + d);
    }

    // gate[n] = 16 * masked[b,n] / (sum_b' masked[b',n] + 1e-6), n<8
    if (tid < 8) {
        int n = tid;
        float denom = 1e-6f;
        float mine = 0.f;
        for (int bb = 0; bb < NB; bb++) {
            float v = ((hit[bb] >> n) & 1u) ? s0[bb * NE + n] : 0.f;
            denom += v;
            if (bb == b) mine = v;
        }
        gate[n] = 16.0f * mine / denom;
    }
    __syncthreads();

    // fc1: thread c computes column c of h1 for all 18 positions
    {
        int c = tid;
        float acc[18];
        #pragma unroll
        for (int p = 0; p < 18; p++) acc[p] = 0.f;
        for (int d = 0; d < DIM; d++) {
            float w = ld<F32>(W1, (size_t)d * HID + c);
            #pragma unroll
            for (int p = 0; p < 18; p++) acc[p] += xs[p][d] * w;
        }
        float b1 = ld<F32>(B1, c);
        #pragma unroll
        for (int p = 0; p < 18; p++) h1[p / 9][p % 9][c] = acc[p] + b1;
    }
    __syncthreads();

    // depthwise 3x3 (SAME) at h=0, w=0..7, + bias + exact gelu
    {
        int c = tid;
        float wd1[3], wd2[3];   // kernel rows kh=1 (input row 0), kh=2 (input row 1)
        #pragma unroll
        for (int dw = 0; dw < 3; dw++) {
            wd1[dw] = ld<F32>(Wd, (size_t)(3 + dw) * HID + c);
            wd2[dw] = ld<F32>(Wd, (size_t)(6 + dw) * HID + c);
        }
        float bd = ld<F32>(Bd, c);
        #pragma unroll
        for (int w = 0; w < 8; w++) {
            float y = bd;
            #pragma unroll
            for (int dw = 0; dw < 3; dw++) {
                int col = w - 1 + dw;
                if (col >= 0) {   // col <= 8 always in-range
                    y += h1[0][col][c] * wd1[dw] + h1[1][col][c] * wd2[dw];
                }
            }
            gl[w][c] = 0.5f * y * (1.0f + erff(y * 0.70710678118654752f));
        }
    }
    __syncthreads();

    // fc2: thread -> (w = tid>>7 and w+4, o = tid&127)
    {
        int o = tid & 127;
        int w0 = tid >> 7;     // 0..3
        int w1i = w0 + 4;
        float a0 = 0.f, a1 = 0.f;
        for (int c = 0; c < HID; c++) {
            float wv = ld<F32>(W2, (size_t)c * NOUT + o);
            a0 += gl[w0][c] * wv;
            a1 += gl[w1i][c] * wv;
        }
        float b2 = ld<F32>(B2, o);
        a0 = (a0 + b2) * gate[w0];
        a1 = (a1 + b2) * gate[w1i];
        st<F32>(out, ((size_t)b * NTOK + w0) * NOUT + o, a0);
        st<F32>(out, ((size_t)b * NTOK + w1i) * NOUT + o, a1);
    }
}

extern "C" void kernel_launch(void* const* d_in, const int* in_sizes, int n_in,
                              void* d_out, int out_size, void* d_ws, size_t ws_size,
                              hipStream_t stream) {
    const void* x  = d_in[0];
    // d_in[1] = H, d_in[2] = W (ints) — fixed 64x64, hard-coded
    const void* wg = d_in[3];
    const void* bg = d_in[4];
    const void* W1 = d_in[5];
    const void* B1 = d_in[6];
    const void* Wd = d_in[7];
    const void* Bd = d_in[8];
    const void* W2 = d_in[9];
    const void* B2 = d_in[10];

    float* s0        = (float*)d_ws;
    unsigned int* hit  = (unsigned int*)((char*)d_ws + 512);
    unsigned int* flag = (unsigned int*)((char*)d_ws + 576);

    detect_kernel<<<1, 64, 0, stream>>>((const unsigned short*)x, s0, hit, flag);

    gate_kernel<false><<<NB * NTOK / 256, 256, 0, stream>>>(x, wg, bg, s0, hit, flag, d_out);
    gate_kernel<true ><<<NB * NTOK / 256, 256, 0, stream>>>(x, wg, bg, s0, hit, flag, d_out);

    expert_kernel<false><<<NB, 512, 0, stream>>>(x, W1, B1, Wd, Bd, W2, B2, s0, hit, flag, d_out);
    expert_kernel<true ><<<NB, 512, 0, stream>>>(x, W1, B1, Wd, Bd, W2, B2, s0, hit, flag, d_out);
}

// Round 3
// 141.890 us; speedup vs baseline: 1.6886x; 1.6886x over previous
//
#include <hip/hip_runtime.h>
#include <math.h>

#define NB   16      // batch
#define NTOK 4096    // N = 64*64
#define DIM  128
#define NE   8
#define HID  512
#define NOUT 128
#define TPT  16                              // threads per token
#define GBLOCKS (NB * NTOK * TPT / 256)      // 4096 blocks

// ws layout: s0[16*8] float (512 B) | hitpart[4096] bytes  -> 4608 B total.
// Every ws byte we read is unconditionally written first (harness poisons ws).

// 16 lanes per token: coalesced float4 reads of x, butterfly-reduced gate
// logits, per-block hit bitmask (no global atomics), softmax score for
// expert 0 at n<8, and zero-fill of the output rows.
__global__ __launch_bounds__(256) void gate_kernel(
    const float4* __restrict__ x,        // (16,4096,128) f32 as float4[2097152]
    const float* __restrict__ wg,        // (128,8)
    const float* __restrict__ bg,        // (8)
    float* __restrict__ s0,              // ws (16,8)
    unsigned char* __restrict__ hitpart, // ws (4096) one byte per block
    float4* __restrict__ out)            // (16,4096,128) f32
{
    __shared__ float4 lw4[NE][DIM / 4];  // wg transposed: lw4[e][s] = wg[s*4..s*4+3, e]
    __shared__ float lbg[NE];
    __shared__ unsigned int lmask;

    int tid = threadIdx.x;
    {   // stage wg transposed (one float4 per thread)
        int e = tid >> 5, s = tid & 31, d0 = s * 4;
        float4 w;
        w.x = wg[(d0 + 0) * NE + e];
        w.y = wg[(d0 + 1) * NE + e];
        w.z = wg[(d0 + 2) * NE + e];
        w.w = wg[(d0 + 3) * NE + e];
        lw4[e][s] = w;
    }
    if (tid < NE) lbg[tid] = bg[tid];
    if (tid == 0) lmask = 0u;
    __syncthreads();

    int g   = blockIdx.x * 256 + tid;
    int tok = g >> 4;        // token id 0..65535
    int sub = g & 15;        // lane-within-token
    int b   = tok >> 12;
    int n   = tok & 4095;

    // this lane's 8 dims: [sub*4, sub*4+4) and [64+sub*4, 64+sub*4+4)
    float4 xa = x[(size_t)tok * 32 + sub];
    float4 xb = x[(size_t)tok * 32 + sub + 16];

    float z[NE];
    #pragma unroll
    for (int e = 0; e < NE; e++) {
        float4 wa = lw4[e][sub];
        float4 wb = lw4[e][sub + 16];
        z[e] = xa.x * wa.x + xa.y * wa.y + xa.z * wa.z + xa.w * wa.w
             + xb.x * wb.x + xb.y * wb.y + xb.z * wb.z + xb.w * wb.w;
    }

    // butterfly sum across the 16 lanes of this token (masks 1,2,4,8)
    #pragma unroll
    for (int off = 1; off <= 8; off <<= 1) {
        #pragma unroll
        for (int e = 0; e < NE; e++) z[e] += __shfl_xor(z[e], off);
    }

    if (sub == 0) {
        float zf[NE];
        #pragma unroll
        for (int e = 0; e < NE; e++) zf[e] = z[e] + lbg[e];

        // argmax, first occurrence of max (jnp.argmax semantics)
        int am = 0;
        float mz = zf[0];
        #pragma unroll
        for (int e = 1; e < NE; e++) {
            if (zf[e] > mz) { mz = zf[e]; am = e; }
        }
        atomicOr(&lmask, 1u << am);   // LDS atomic, 16 per block

        if (n < 8) {                   // softmax score for expert 0
            float s = 0.f;
            #pragma unroll
            for (int e = 0; e < NE; e++) s += expf(zf[e] - mz);
            s0[b * NE + n] = expf(zf[0] - mz) / s;
        }
    }

    // zero-fill this token's output slice (expert kernel overwrites n<8 later)
    float4 zz = make_float4(0.f, 0.f, 0.f, 0.f);
    out[(size_t)tok * 32 + sub]      = zz;
    out[(size_t)tok * 32 + sub + 16] = zz;

    __syncthreads();
    if (tid == 0) hitpart[blockIdx.x] = (unsigned char)lmask;
}

// One block per batch image. Expert-0 MixFFN for the 8 nonzero tokens:
// fc1 at 18 positions (rows 0-1, cols 0-8) -> dwconv(h=0,w=0..7) -> gelu ->
// fc2, scaled by the (buggy-scatter) gate.
__global__ __launch_bounds__(512) void expert_kernel(
    const float* __restrict__ x,
    const float* __restrict__ W1,   // (8,128,512) -> expert 0 slice
    const float* __restrict__ B1,   // (8,512)
    const float* __restrict__ Wd,   // (8,3,3,1,512)
    const float* __restrict__ Bd,   // (8,512)
    const float* __restrict__ W2,   // (8,512,128)
    const float* __restrict__ B2,   // (8,128)
    const float* __restrict__ s0,
    const unsigned char* __restrict__ hitpart,
    float* __restrict__ out)
{
    __shared__ float xs[18][DIM];     //  9216 B
    __shared__ float h1[2][9][HID];   // 36864 B
    __shared__ float gl[8][HID];      // 16384 B
    __shared__ float gate[8];
    __shared__ unsigned int hmask[NB];

    int b = blockIdx.x;
    int tid = threadIdx.x;

    if (tid < NB) hmask[tid] = 0u;

    // stage x at (row 0..1, col 0..8)
    for (int i = tid; i < 18 * DIM; i += 512) {
        int p = i / DIM, d = i % DIM;
        int row = p / 9, col = p % 9;
        int nn = row * 64 + col;
        xs[p][d] = x[((size_t)b * NTOK + nn) * DIM + d];
    }

    // per-thread OR of 16 hitpart bytes (256 threads cover all 4096 blocks)
    unsigned int hm = 0u;
    int hb = 0;
    if (tid < 256) {
        uint4 v = ((const uint4*)hitpart)[tid];
        hm = v.x | v.y | v.z | v.w;
        hm |= hm >> 16; hm |= hm >> 8; hm &= 0xffu;
        hb = tid >> 4;   // 16 threads per batch (256 bytes each batch)
    }
    __syncthreads();
    if (tid < 256) atomicOr(&hmask[hb], hm);
    __syncthreads();

    // gate[n] = 16 * masked[b,n] / (sum_b' masked[b',n] + 1e-6), n<8
    if (tid < 8) {
        int nn = tid;
        float denom = 1e-6f;
        float mine = 0.f;
        for (int bb = 0; bb < NB; bb++) {
            float v = ((hmask[bb] >> nn) & 1u) ? s0[bb * NE + nn] : 0.f;
            denom += v;
            if (bb == b) mine = v;
        }
        gate[nn] = 16.0f * mine / denom;
    }

    // fc1: thread c computes column c of h1 for all 18 positions
    {
        int c = tid;
        float acc[18];
        #pragma unroll
        for (int p = 0; p < 18; p++) acc[p] = 0.f;
        for (int d = 0; d < DIM; d++) {
            float w = W1[(size_t)d * HID + c];
            #pragma unroll
            for (int p = 0; p < 18; p++) acc[p] += xs[p][d] * w;
        }
        float b1 = B1[c];
        #pragma unroll
        for (int p = 0; p < 18; p++) h1[p / 9][p % 9][c] = acc[p] + b1;
    }
    __syncthreads();

    // depthwise 3x3 (SAME) at h=0, w=0..7, + bias + exact gelu
    {
        int c = tid;
        float wd1[3], wd2[3];   // kernel rows kh=1 (input row 0), kh=2 (input row 1)
        #pragma unroll
        for (int dw = 0; dw < 3; dw++) {
            wd1[dw] = Wd[(size_t)(3 + dw) * HID + c];
            wd2[dw] = Wd[(size_t)(6 + dw) * HID + c];
        }
        float bd = Bd[c];
        #pragma unroll
        for (int w = 0; w < 8; w++) {
            float y = bd;
            #pragma unroll
            for (int dw = 0; dw < 3; dw++) {
                int col = w - 1 + dw;
                if (col >= 0) {   // col <= 8 always in-range
                    y += h1[0][col][c] * wd1[dw] + h1[1][col][c] * wd2[dw];
                }
            }
            gl[w][c] = 0.5f * y * (1.0f + erff(y * 0.70710678118654752f));
        }
    }
    __syncthreads();

    // fc2: thread -> (w = tid>>7 and w+4, o = tid&127)
    {
        int o = tid & 127;
        int w0 = tid >> 7;     // 0..3
        int w1i = w0 + 4;
        float a0 = 0.f, a1 = 0.f;
        for (int c = 0; c < HID; c++) {
            float wv = W2[(size_t)c * NOUT + o];
            a0 += gl[w0][c] * wv;
            a1 += gl[w1i][c] * wv;
        }
        float b2 = B2[o];
        a0 = (a0 + b2) * gate[w0];
        a1 = (a1 + b2) * gate[w1i];
        out[((size_t)b * NTOK + w0) * NOUT + o]  = a0;
        out[((size_t)b * NTOK + w1i) * NOUT + o] = a1;
    }
}

extern "C" void kernel_launch(void* const* d_in, const int* in_sizes, int n_in,
                              void* d_out, int out_size, void* d_ws, size_t ws_size,
                              hipStream_t stream) {
    const float* x  = (const float*)d_in[0];
    // d_in[1] = H, d_in[2] = W (ints) — fixed 64x64, hard-coded
    const float* wg = (const float*)d_in[3];
    const float* bg = (const float*)d_in[4];
    const float* W1 = (const float*)d_in[5];
    const float* B1 = (const float*)d_in[6];
    const float* Wd = (const float*)d_in[7];
    const float* Bd = (const float*)d_in[8];
    const float* W2 = (const float*)d_in[9];
    const float* B2 = (const float*)d_in[10];

    float* s0              = (float*)d_ws;
    unsigned char* hitpart = (unsigned char*)d_ws + 512;

    gate_kernel<<<GBLOCKS, 256, 0, stream>>>(
        (const float4*)x, wg, bg, s0, hitpart, (float4*)d_out);
    expert_kernel<<<NB, 512, 0, stream>>>(
        x, W1, B1, Wd, Bd, W2, B2, s0, hitpart, (float*)d_out);
}